// Round 5
// baseline (216.269 us; speedup 1.0000x reference)
//
#include <hip/hip_runtime.h>

// CollisionLoss: B x (7 left) x (7 right) segment-segment squared distances,
// masked exp(-d2) sum / B.
//
// R9 == R8 resubmit (R8 bench died on container acquisition, not kernel):
// occupancy/concurrency rework (Little's-law theory). Timeline: 2x78us
// harness fills (fixed) + ~58us kernel vs ~13-18us roofline. Achieved kernel
// BW ~1.9TB/s AND VALU ~20% => both pipes idle => waves are parked in
// memory-wait together: per-CU miss concurrency (MSHR/line-lookup) is the
// limiter and 12 waves/CU (3 blocks x 4 waves, 43KB LDS) can't cover ~900cy
// latency. All prior rounds varied data-path SHAPE, never occupancy.
// Fix: (1) 2 threads/row -> per-thread work halves (s=0: right segs 0..3,
// s=1: segs 4,5 + special row); (2) BT=256 over 128 rows keeps LDS at
// 21.5KB -> 7 blocks/CU = 28 waves/CU (2.3x); (3) __launch_bounds__(256,8)
// pins VGPR<=64 (occupancy cliff at 64/128) -- persistent state is only
// n0..n6+hl+sums (~30 regs), rd/n13/hr loaded inside the s==1 tail.
// Staging stays coalesced float4 (whole block stages 1344 float4 linearly);
// loop over right segs kept rolled (R7's I$ fix, ~4us, retained).

__device__ __forceinline__ float rcpf(float x) { return __builtin_amdgcn_rcpf(x); }
__device__ __forceinline__ float clamp01(float x) {
    return __builtin_amdgcn_fmed3f(x, 0.0f, 1.0f);
}

__device__ __forceinline__ float cap_dist2(
    float px0, float py0, float pz0, float px1, float py1, float pz1,
    float qx0, float qy0, float qz0, float qx1, float qy1, float qz1)
{
    const float dpx = px1 - px0, dpy = py1 - py0, dpz = pz1 - pz0;
    const float dqx = qx1 - qx0, dqy = qy1 - qy0, dqz = qz1 - qz0;
    const float rx  = px0 - qx0, ry  = py0 - qy0, rz  = pz0 - qz0;

    const float a = dpx*dpx + dpy*dpy + dpz*dpz;   // >0 w.p. 1 (gaussian)
    const float c = dqx*dqx + dqy*dqy + dqz*dqz;   // >0 w.p. 1
    const float b = dpx*dqx + dpy*dqy + dpz*dqz;
    const float d = dpx*rx + dpy*ry + dpz*rz;
    const float e = dqx*rx + dqy*ry + dqz*rz;
    const float det = a*c - b*b;

    const float rcp_a = rcpf(a);
    const float rcp_c = rcpf(c);

    // s0 = det>0 ? clamp01((be-cd)/det) : 0  (cndmask kills the inf/NaN path)
    const float f  = b*e - c*d;
    const float s0 = (det > 0.0f) ? clamp01(f * rcpf(det)) : 0.0f;

    const float tn = b*s0 + e;                 // t numerator (denominator c)
    const float t  = clamp01(tn * rcp_c);

    // recompute s only where t was clamped (two cndmasks); ties measure-zero
    const float sA = clamp01(-d * rcp_a);          // t clamped to 0
    const float sB = clamp01((b - d) * rcp_a);     // t clamped to 1
    const float s  = (tn < 0.0f) ? sA : ((tn > c) ? sB : s0);

    const float wx = rx + s*dpx - t*dqx;
    const float wy = ry + s*dpy - t*dqy;
    const float wz = rz + s*dpz - t*dqz;
    return wx*wx + wy*wy + wz*wz;
}

#define BT 256   // 4 waves; 128 rows per block (2 threads per row)

__global__ __launch_bounds__(BT, 8) void collision_loss_kernel(
    const float* __restrict__ pos,
    const float* __restrict__ rot,
    float* __restrict__ out)
{
    __shared__ float4 sb4[1344];   // 128 rows x 168 B = 21504 B
    __shared__ float wsum[4];

    const int tid     = threadIdx.x;
    const int lane    = tid & 63;
    const int wave    = tid >> 6;        // 0..3
    const int slabIdx = tid >> 7;        // which 64-row half of the block
    const int s       = (tid >> 6) & 1;  // pair-subset: 0 -> i=0..3, 1 -> i=4..6
    const int r       = tid & 63;        // row within half

    // ---- coalesced stage: whole block copies its 1344 float4 linearly ----
    const float4* g4 = reinterpret_cast<const float4*>(pos) + (size_t)blockIdx.x * 1344;
    #pragma unroll
    for (int k = 0; k < 5; ++k) sb4[k * 256 + tid] = g4[k * 256 + tid];
    if (tid < 64) sb4[1280 + tid] = g4[1280 + tid];   // wave0 tail, wave-uniform

    // ---- rot r6 (node6 col2) for handL: needed by BOTH subsets; issued here
    //      so its latency overlaps the staging drain ----
    const int myRow = blockIdx.x * 128 + slabIdx * 64 + r;
    const float* rb = rot + (size_t)myRow * 126;
    const float r6x = rb[56], r6y = rb[59], r6z = rb[62];

    __syncthreads();

    // ---- readback LEFT nodes n0..n6 (floats 0..20 of own row) ----
    const float* sf = reinterpret_cast<const float*>(sb4)
                      + (size_t)(slabIdx * 64 + r) * 42;
    const float2* m2 = reinterpret_cast<const float2*>(sf);
    const float2 u0 = m2[0], u1 = m2[1], u2 = m2[2], u3 = m2[3], u4 = m2[4];
    const float2 u5 = m2[5], u6 = m2[6], u7 = m2[7], u8 = m2[8], u9 = m2[9];
    const float2 u10 = m2[10];

    const float n0x=u0.x,  n0y=u0.y,  n0z=u1.x;
    const float n1x=u1.y,  n1y=u2.x,  n1z=u2.y;
    const float n2x=u3.x,  n2y=u3.y,  n2z=u4.x;
    const float n3x=u4.y,  n3y=u5.x,  n3z=u5.y;
    const float n4x=u6.x,  n4y=u6.y,  n4z=u7.x;
    const float n5x=u7.y,  n5y=u8.x,  n5z=u8.y;
    const float n6x=u9.x,  n6y=u9.y,  n6z=u10.x;

    const float hlx = n6x + 0.2f * r6x;   // handL = node6 + 0.2*col2
    const float hly = n6y + 0.2f * r6y;
    const float hlz = n6z + 0.2f * r6z;

    float sum0 = 0.0f, sum1 = 0.0f;       // two chains: halve serial add path

    auto acc = [&](float& s_, float p0x, float p0y, float p0z,
                   float p1x, float p1y, float p1z,
                   float q0x, float q0y, float q0z,
                   float q1x, float q1y, float q1z, bool special) {
        const float d2 = cap_dist2(p0x,p0y,p0z, p1x,p1y,p1z,
                                   q0x,q0y,q0z, q1x,q1y,q1z);
        const bool m = special ? (d2 > 0.09f)
                               : ((d2 < 0.01f) && (d2 > 0.0f));
        s_ += m ? __expf(-d2) : 0.0f;
    };

    // all 7 left pairs vs one right seg (q0,q1); special only on peeled row
    #define LROW(QX0,QY0,QZ0,QX1,QY1,QZ1,SP)                                  \
        acc(sum0, n0x,n0y,n0z, n1x,n1y,n1z, QX0,QY0,QZ0, QX1,QY1,QZ1, false); \
        acc(sum1, n1x,n1y,n1z, n2x,n2y,n2z, QX0,QY0,QZ0, QX1,QY1,QZ1, false); \
        acc(sum0, n2x,n2y,n2z, n3x,n3y,n3z, QX0,QY0,QZ0, QX1,QY1,QZ1, false); \
        acc(sum1, n3x,n3y,n3z, n4x,n4y,n4z, QX0,QY0,QZ0, QX1,QY1,QZ1, false); \
        acc(sum0, n4x,n4y,n4z, n5x,n5y,n5z, QX0,QY0,QZ0, QX1,QY1,QZ1, false); \
        acc(sum1, n5x,n5y,n5z, n6x,n6y,n6z, QX0,QY0,QZ0, QX1,QY1,QZ1, false); \
        acc(sum0, n6x,n6y,n6z, hlx,hly,hlz, QX0,QY0,QZ0, QX1,QY1,QZ1, SP);

    // ---- rolled loop over this subset's regular right segs (I$-resident) ----
    // s=0: i=0..3 (28 pairs); s=1: i=4..5 (14 pairs) + special row (7) = 21.
    const int iLo = s ? 4 : 0;
    const int iHi = s ? 6 : 4;
    #pragma clang loop unroll(disable)
    for (int i = iLo; i < iHi; ++i) {
        const int f0 = 21 + 3 * i;                 // node(7+i) first float
        const float q0x = sf[f0    ], q0y = sf[f0 + 1], q0z = sf[f0 + 2];
        const float q1x = sf[f0 + 3], q1y = sf[f0 + 4], q1z = sf[f0 + 5];
        LROW(q0x,q0y,q0z, q1x,q1y,q1z, false)
    }

    // ---- s==1 tail: special right seg (n13, handR); short live ranges ----
    if (s) {
        const float rdx = rb[119], rdy = rb[122], rdz = rb[125];  // node13 col2
        const float n13x = sf[39], n13y = sf[40], n13z = sf[41];
        const float hrx = n13x + 0.2f * rdx;
        const float hry = n13y + 0.2f * rdy;
        const float hrz = n13z + 0.2f * rdz;
        LROW(n13x,n13y,n13z, hrx,hry,hrz, true)
    }
    #undef LROW

    float sum = sum0 + sum1;

    // ---- reduction: wave shuffle -> LDS -> one atomic per block (2048) ----
    #pragma unroll
    for (int off = 32; off > 0; off >>= 1)
        sum += __shfl_down(sum, off, 64);
    if (lane == 0) wsum[wave] = sum;
    __syncthreads();
    if (tid == 0) {
        atomicAdd(out, (wsum[0] + wsum[1] + wsum[2] + wsum[3])
                       * (1.0f / 262144.0f));      // /B exact
    }
}

extern "C" void kernel_launch(void* const* d_in, const int* in_sizes, int n_in,
                              void* d_out, int out_size, void* d_ws, size_t ws_size,
                              hipStream_t stream) {
    const float* pos = (const float*)d_in[0];   // (B,14,3) f32
    const float* rot = (const float*)d_in[1];   // (B,14,9) f32
    float* out = (float*)d_out;

    const int B = in_sizes[0] / 42;             // 262144 (multiple of 128)
    hipMemsetAsync(out, 0, sizeof(float), stream);

    collision_loss_kernel<<<B / 128, BT, 0, stream>>>(pos, rot, out);
}